// Round 5
// baseline (526.428 us; speedup 1.0000x reference)
//
#include <hip/hip_runtime.h>
#include <math.h>

#define NPTS   (1u << 20)
#define NLVL   16
#define NSTAGE 14               // levels 0..13 staged; 14,15 inline in transpose
#define TBITS  19
#define TMASK  ((1u << TBITS) - 1u)
#define CHUNKS (NPTS / 256u)    // 4096 blocks per level
#define NBINS  32768            // 32^3 Morton buckets

struct ScaleParams { float s[NLVL]; };

// ---------------------------------------------------------------------------
// Pair loader: fetch table[iF] and table[iC] with the fewest 64B-line touches.
// m==1  -> one aligned float4 (1 line).
// |d|==1 -> one 8B-aligned dwordx4 covering both entries (1 line).
// else  -> two independent gathers (1-2 lines).
// ---------------------------------------------------------------------------
__device__ __forceinline__ void load_pair(const float2* __restrict__ t,
                                          uint32_t iF, uint32_t iC,
                                          float2& vF, float2& vC)
{
    const uint32_t d = iF ^ iC;
    if (d == 1u) {
        const float4 q = *(const float4*)(t + (iF & ~1u));
        if (iF & 1u) { vF = make_float2(q.z, q.w); vC = make_float2(q.x, q.y); }
        else         { vF = make_float2(q.x, q.y); vC = make_float2(q.z, q.w); }
    } else if (iC == iF + 1u || iF == iC + 1u) {
        const uint32_t lo = (iF < iC) ? iF : iC;
        const float4 q = *(const float4*)(t + lo);      // 8B-aligned dwordx4
        if (iF == lo) { vF = make_float2(q.x, q.y); vC = make_float2(q.z, q.w); }
        else          { vF = make_float2(q.z, q.w); vC = make_float2(q.x, q.y); }
    } else {
        vF = t[iF]; vC = t[iC];
    }
}

// Full per-(point,level) evaluation; bit-identical arithmetic to the reference.
__device__ __forceinline__ float2 eval_level(float x0, float x1, float x2,
                                             float s, uint32_t l,
                                             const float2* __restrict__ table)
{
    const float sx = x0 * s, sy = x1 * s, sz = x2 * s;
    const float fxf = floorf(sx), fyf = floorf(sy), fzf = floorf(sz);
    const float cxf = ceilf(sx),  cyf = ceilf(sy),  czf = ceilf(sz);
    const float ox = sx - fxf, oy = sy - fyf, oz = sz - fzf;

    const uint32_t PR1 = 2654435761u, PR2 = 805459861u;
    const uint32_t fx = (uint32_t)fxf, cx = (uint32_t)cxf;
    const uint32_t Yf = (uint32_t)fyf * PR1,  Yc = (uint32_t)cyf * PR1;
    const uint32_t Zf = (uint32_t)fzf * PR2,  Zc = (uint32_t)czf * PR2;
    const uint32_t base = l << TBITS;

    const uint32_t i0 = ((cx ^ Yc ^ Zc) & TMASK) + base;  // [1,1,1]
    const uint32_t i1 = ((cx ^ Yf ^ Zc) & TMASK) + base;  // [1,0,1]
    const uint32_t i2 = ((fx ^ Yf ^ Zc) & TMASK) + base;  // [0,0,1]
    const uint32_t i3 = ((fx ^ Yc ^ Zc) & TMASK) + base;  // [0,1,1]
    const uint32_t i4 = ((cx ^ Yc ^ Zf) & TMASK) + base;  // [1,1,0]
    const uint32_t i5 = ((cx ^ Yf ^ Zf) & TMASK) + base;  // [1,0,0]
    const uint32_t i6 = ((fx ^ Yf ^ Zf) & TMASK) + base;  // [0,0,0]
    const uint32_t i7 = ((fx ^ Yc ^ Zf) & TMASK) + base;  // [0,1,0]

    float2 f0, f1, f2, f3, f4, f5, f6, f7;
    load_pair(table, i3, i0, f3, f0);
    load_pair(table, i2, i1, f2, f1);
    load_pair(table, i7, i4, f7, f4);
    load_pair(table, i6, i5, f6, f5);

    const float omx = 1.0f - ox, omy = 1.0f - oy, omz = 1.0f - oz;
    const float a0 = f0.x * ox + f3.x * omx, b0 = f0.y * ox + f3.y * omx;
    const float a1 = f1.x * ox + f2.x * omx, b1 = f1.y * ox + f2.y * omx;
    const float a2 = f5.x * ox + f6.x * omx, b2 = f5.y * ox + f6.y * omx;
    const float a3 = f4.x * ox + f7.x * omx, b3 = f4.y * ox + f7.y * omx;
    const float c0 = a0 * oy + a1 * omy, d0 = b0 * oy + b1 * omy;
    const float c1 = a3 * oy + a2 * omy, d1 = b3 * oy + b2 * omy;
    return make_float2(c0 * oz + c1 * omz, d0 * oz + d1 * omz);
}

// --------------------------- Morton key (32^3) -----------------------------
__device__ __forceinline__ uint32_t part1by2(uint32_t v)
{
    v &= 0x3FFu;
    v = (v | (v << 16)) & 0x030000FFu;
    v = (v | (v << 8))  & 0x0300F00Fu;
    v = (v | (v << 4))  & 0x030C30C3u;
    v = (v | (v << 2))  & 0x09249249u;
    return v;
}
__device__ __forceinline__ uint32_t morton_key(float x0, float x1, float x2)
{
    uint32_t kx = (uint32_t)(x0 * 32.0f); kx = kx > 31u ? 31u : kx;
    uint32_t ky = (uint32_t)(x1 * 32.0f); ky = ky > 31u ? 31u : ky;
    uint32_t kz = (uint32_t)(x2 * 32.0f); kz = kz > 31u ? 31u : kz;
    return part1by2(kx) | (part1by2(ky) << 1) | (part1by2(kz) << 2);
}

// ------------------------------ sort kernels -------------------------------
__global__ __launch_bounds__(256)
void zero_hist_kernel(uint32_t* __restrict__ hist)
{
    hist[blockIdx.x * 256u + threadIdx.x] = 0u;
}

__global__ __launch_bounds__(256)
void hist_kernel(const float* __restrict__ x, uint32_t* __restrict__ hist)
{
    const uint32_t p = blockIdx.x * 256u + threadIdx.x;
    const uint32_t key = morton_key(x[p*3+0], x[p*3+1], x[p*3+2]);
    atomicAdd(&hist[key], 1u);
}

// exclusive prefix sum over NBINS, single 1024-thread block (32 bins/thread)
__global__ __launch_bounds__(1024)
void scan_kernel(const uint32_t* __restrict__ hist, uint32_t* __restrict__ offs)
{
    __shared__ uint32_t part[1024];
    const uint32_t tid = threadIdx.x;
    uint32_t local[32];
    uint32_t sum = 0;
    #pragma unroll
    for (int i = 0; i < 32; ++i) { local[i] = hist[tid * 32u + i]; sum += local[i]; }
    part[tid] = sum;
    __syncthreads();
    for (uint32_t off = 1; off < 1024u; off <<= 1) {
        uint32_t v = (tid >= off) ? part[tid - off] : 0u;
        __syncthreads();
        part[tid] += v;
        __syncthreads();
    }
    uint32_t run = (tid ? part[tid - 1] : 0u);   // exclusive base
    #pragma unroll
    for (int i = 0; i < 32; ++i) { offs[tid * 32u + i] = run; run += local[i]; }
}

__global__ __launch_bounds__(256)
void scatter_kernel(const float* __restrict__ x, uint32_t* __restrict__ offs,
                    float4* __restrict__ rec)
{
    const uint32_t p = blockIdx.x * 256u + threadIdx.x;
    const float x0 = x[p*3+0], x1 = x[p*3+1], x2 = x[p*3+2];
    const uint32_t key = morton_key(x0, x1, x2);
    const uint32_t pos = atomicAdd(&offs[key], 1u);
    rec[pos] = make_float4(x0, x1, x2, __uint_as_float(p));
}

// ------------------------- main gather (levels 0..13) ----------------------
__global__ __launch_bounds__(256)
void gather_sorted(const float4* __restrict__ rec,
                   const float2* __restrict__ table,
                   float2* __restrict__ stage,
                   ScaleParams P)
{
    const uint32_t l  = blockIdx.x / CHUNKS;     // level-phased for L2 residency
    const uint32_t c  = blockIdx.x % CHUNKS;
    const uint32_t sp = c * 256u + threadIdx.x;  // sorted position

    const float4 r = rec[sp];
    stage[l * NPTS + sp] = eval_level(r.x, r.y, r.z, P.s[l], l, table);
}

// -------- transpose + inline levels 14,15 + un-permute to d_out -------------
__global__ __launch_bounds__(256)
void transpose_fused(const float4* __restrict__ rec,
                     const float2* __restrict__ stage,
                     const float2* __restrict__ table,
                     float* __restrict__ out,
                     ScaleParams P)
{
    const uint32_t sp = blockIdx.x * 256u + threadIdx.x;
    const float4 r = rec[sp];
    const uint32_t orig = __float_as_uint(r.w);

    float2 v[NLVL];
    #pragma unroll
    for (int l = 0; l < NSTAGE; ++l) v[l] = stage[(uint32_t)l * NPTS + sp];
    v[14] = eval_level(r.x, r.y, r.z, P.s[14], 14u, table);
    v[15] = eval_level(r.x, r.y, r.z, P.s[15], 15u, table);

    float4* o4 = (float4*)(out + (size_t)orig * 32u);
    #pragma unroll
    for (int j = 0; j < 8; ++j)
        o4[j] = make_float4(v[2*j].x, v[2*j].y, v[2*j+1].x, v[2*j+1].y);
}

// ------------------------------ fused fallback ------------------------------
__global__ __launch_bounds__(256)
void hashenc_fused(const float* __restrict__ x,
                   const float2* __restrict__ table,
                   float2* __restrict__ out,
                   ScaleParams P)
{
    const uint32_t tid = blockIdx.x * 256u + threadIdx.x;
    const uint32_t p = tid >> 4;
    const uint32_t l = tid & 15u;
    out[p * 16u + l] = eval_level(x[p*3+0], x[p*3+1], x[p*3+2], P.s[l], l, table);
}

extern "C" void kernel_launch(void* const* d_in, const int* in_sizes, int n_in,
                              void* d_out, int out_size, void* d_ws, size_t ws_size,
                              hipStream_t stream) {
    const float*  x     = (const float*)d_in[0];
    const float2* table = (const float2*)d_in[1];

    // SCALINGS: replicate numpy float64 pipeline in identical op order.
    ScaleParams P;
    const double growth = exp((log(4096.0) - log(16.0)) / 15.0);
    for (int l = 0; l < NLVL; ++l)
        P.s[l] = (float)floor(16.0 * pow(growth, (double)l));

    // ws layout: rec (16 MiB) | stage levels 0..13 (112 MiB)  == 128 MiB total
    const size_t ws_needed = (size_t)NPTS * sizeof(float4)
                           + (size_t)NPTS * NSTAGE * sizeof(float2);

    if (ws_size >= ws_needed) {
        float4* rec   = (float4*)d_ws;
        float2* stage = (float2*)((char*)d_ws + (size_t)NPTS * sizeof(float4));
        // hist/offs scratch lives in d_out (dead before output is written)
        uint32_t* hist = (uint32_t*)d_out;
        uint32_t* offs = (uint32_t*)d_out + NBINS;

        dim3 b256(256u);
        hipLaunchKernelGGL(zero_hist_kernel, dim3(NBINS / 256u), b256, 0, stream, hist);
        hipLaunchKernelGGL(hist_kernel,      dim3(NPTS / 256u),  b256, 0, stream, x, hist);
        hipLaunchKernelGGL(scan_kernel,      dim3(1),  dim3(1024u), 0, stream, hist, offs);
        hipLaunchKernelGGL(scatter_kernel,   dim3(NPTS / 256u),  b256, 0, stream, x, offs, rec);
        hipLaunchKernelGGL(gather_sorted,    dim3(NSTAGE * CHUNKS), b256, 0, stream,
                           rec, table, stage, P);
        hipLaunchKernelGGL(transpose_fused,  dim3(NPTS / 256u),  b256, 0, stream,
                           rec, stage, table, (float*)d_out, P);
    } else {
        float2* out = (float2*)d_out;
        hipLaunchKernelGGL(hashenc_fused, dim3(NPTS * NLVL / 256u), dim3(256u), 0, stream,
                           x, table, out, P);
    }
}

// Round 6
// 455.632 us; speedup vs baseline: 1.1554x; 1.1554x over previous
//
#include <hip/hip_runtime.h>
#include <hip/hip_fp16.h>
#include <math.h>

#define NPTS   (1u << 20)
#define NLVL   16
#define NGRID  5                 // levels 0..4 via dense vertex grids
#define TBITS  19
#define TMASK  ((1u << TBITS) - 1u)
#define CHUNKS (NPTS / 256u)     // 4096 blocks per level
#define NBINS  32768             // 32^3 Morton buckets
#define PR1    2654435761u
#define PR2    805459861u

struct Params {
    float    s[NLVL];
    uint32_t gdim[NGRID];        // vertices per axis (s+1)
    uint32_t goff[NGRID];        // float2 offset of each grid in gridbuf
    uint32_t vcum[NGRID + 1];    // cumulative vertex counts
};

// ---------------------------------------------------------------------------
// Hash-path pair loader (levels >= NGRID): fewest 64B-line touches.
// ---------------------------------------------------------------------------
__device__ __forceinline__ void load_pair(const float2* __restrict__ t,
                                          uint32_t iF, uint32_t iC,
                                          float2& vF, float2& vC)
{
    const uint32_t d = iF ^ iC;
    if (d == 1u) {
        const float4 q = *(const float4*)(t + (iF & ~1u));
        if (iF & 1u) { vF = make_float2(q.z, q.w); vC = make_float2(q.x, q.y); }
        else         { vF = make_float2(q.x, q.y); vC = make_float2(q.z, q.w); }
    } else if (iC == iF + 1u || iF == iC + 1u) {
        const uint32_t lo = (iF < iC) ? iF : iC;
        const float4 q = *(const float4*)(t + lo);      // 8B-aligned dwordx4
        if (iF == lo) { vF = make_float2(q.x, q.y); vC = make_float2(q.z, q.w); }
        else          { vF = make_float2(q.z, q.w); vC = make_float2(q.x, q.y); }
    } else {
        vF = t[iF]; vC = t[iC];
    }
}

// Shared trilinear tail (bit-identical op order to the reference).
__device__ __forceinline__ float2 lerp8(float2 f0, float2 f1, float2 f2, float2 f3,
                                        float2 f4, float2 f5, float2 f6, float2 f7,
                                        float ox, float oy, float oz)
{
    const float omx = 1.0f - ox, omy = 1.0f - oy, omz = 1.0f - oz;
    const float a0 = f0.x * ox + f3.x * omx, b0 = f0.y * ox + f3.y * omx;
    const float a1 = f1.x * ox + f2.x * omx, b1 = f1.y * ox + f2.y * omx;
    const float a2 = f5.x * ox + f6.x * omx, b2 = f5.y * ox + f6.y * omx;
    const float a3 = f4.x * ox + f7.x * omx, b3 = f4.y * ox + f7.y * omx;
    const float c0 = a0 * oy + a1 * omy, d0 = b0 * oy + b1 * omy;
    const float c1 = a3 * oy + a2 * omy, d1 = b3 * oy + b2 * omy;
    return make_float2(c0 * oz + c1 * omz, d0 * oz + d1 * omz);
}

// Hash-table evaluation (levels >= NGRID).
__device__ __forceinline__ float2 eval_hash(float x0, float x1, float x2,
                                            float s, uint32_t l,
                                            const float2* __restrict__ table)
{
    const float sx = x0 * s, sy = x1 * s, sz = x2 * s;
    const float fxf = floorf(sx), fyf = floorf(sy), fzf = floorf(sz);
    const float cxf = ceilf(sx),  cyf = ceilf(sy),  czf = ceilf(sz);
    const float ox = sx - fxf, oy = sy - fyf, oz = sz - fzf;

    const uint32_t fx = (uint32_t)fxf, cx = (uint32_t)cxf;
    const uint32_t Yf = (uint32_t)fyf * PR1,  Yc = (uint32_t)cyf * PR1;
    const uint32_t Zf = (uint32_t)fzf * PR2,  Zc = (uint32_t)czf * PR2;
    const uint32_t base = l << TBITS;

    const uint32_t i0 = ((cx ^ Yc ^ Zc) & TMASK) + base;
    const uint32_t i1 = ((cx ^ Yf ^ Zc) & TMASK) + base;
    const uint32_t i2 = ((fx ^ Yf ^ Zc) & TMASK) + base;
    const uint32_t i3 = ((fx ^ Yc ^ Zc) & TMASK) + base;
    const uint32_t i4 = ((cx ^ Yc ^ Zf) & TMASK) + base;
    const uint32_t i5 = ((cx ^ Yf ^ Zf) & TMASK) + base;
    const uint32_t i6 = ((fx ^ Yf ^ Zf) & TMASK) + base;
    const uint32_t i7 = ((fx ^ Yc ^ Zf) & TMASK) + base;

    float2 f0, f1, f2, f3, f4, f5, f6, f7;
    load_pair(table, i3, i0, f3, f0);
    load_pair(table, i2, i1, f2, f1);
    load_pair(table, i7, i4, f7, f4);
    load_pair(table, i6, i5, f6, f5);
    return lerp8(f0, f1, f2, f3, f4, f5, f6, f7, ox, oy, oz);
}

// Dense-grid evaluation (levels < NGRID): grid[v] == table[hash(v)], so corner
// values are bit-identical; x-pairs are contiguous -> always 1 load per pair.
__device__ __forceinline__ float2 eval_grid(float x0, float x1, float x2,
                                            float s,
                                            const float2* __restrict__ g,
                                            uint32_t d)
{
    const float sx = x0 * s, sy = x1 * s, sz = x2 * s;
    const float fxf = floorf(sx), fyf = floorf(sy), fzf = floorf(sz);
    const float cxf = ceilf(sx),  cyf = ceilf(sy),  czf = ceilf(sz);
    const float ox = sx - fxf, oy = sy - fyf, oz = sz - fzf;

    const uint32_t fx = (uint32_t)fxf, fy = (uint32_t)fyf, fz = (uint32_t)fzf;
    const uint32_t cy = (uint32_t)cyf, cz = (uint32_t)czf;
    const bool xadj = ((uint32_t)cxf == fx + 1u);   // else cx==fx (integer sx)

    const uint32_t bA = (cz * d + cy) * d + fx;   // (cy,cz): f3(floor-x), f0(ceil-x)
    const uint32_t bB = (cz * d + fy) * d + fx;   // (fy,cz): f2, f1
    const uint32_t bC = (fz * d + cy) * d + fx;   // (cy,fz): f7, f4
    const uint32_t bD = (fz * d + fy) * d + fx;   // (fy,fz): f6, f5
    const float4 qA = *(const float4*)(g + bA);
    const float4 qB = *(const float4*)(g + bB);
    const float4 qC = *(const float4*)(g + bC);
    const float4 qD = *(const float4*)(g + bD);

    const float2 f3 = make_float2(qA.x, qA.y);
    const float2 f0 = xadj ? make_float2(qA.z, qA.w) : f3;
    const float2 f2 = make_float2(qB.x, qB.y);
    const float2 f1 = xadj ? make_float2(qB.z, qB.w) : f2;
    const float2 f7 = make_float2(qC.x, qC.y);
    const float2 f4 = xadj ? make_float2(qC.z, qC.w) : f7;
    const float2 f6 = make_float2(qD.x, qD.y);
    const float2 f5 = xadj ? make_float2(qD.z, qD.w) : f6;
    return lerp8(f0, f1, f2, f3, f4, f5, f6, f7, ox, oy, oz);
}

// --------------------------- Morton key (32^3) -----------------------------
__device__ __forceinline__ uint32_t part1by2(uint32_t v)
{
    v &= 0x3FFu;
    v = (v | (v << 16)) & 0x030000FFu;
    v = (v | (v << 8))  & 0x0300F00Fu;
    v = (v | (v << 4))  & 0x030C30C3u;
    v = (v | (v << 2))  & 0x09249249u;
    return v;
}
__device__ __forceinline__ uint32_t morton_key(float x0, float x1, float x2)
{
    uint32_t kx = (uint32_t)(x0 * 32.0f); kx = kx > 31u ? 31u : kx;
    uint32_t ky = (uint32_t)(x1 * 32.0f); ky = ky > 31u ? 31u : ky;
    uint32_t kz = (uint32_t)(x2 * 32.0f); kz = kz > 31u ? 31u : kz;
    return part1by2(kx) | (part1by2(ky) << 1) | (part1by2(kz) << 2);
}

// ------------------------------ sort kernels -------------------------------
__global__ __launch_bounds__(256)
void zero_hist_kernel(uint32_t* __restrict__ hist)
{
    hist[blockIdx.x * 256u + threadIdx.x] = 0u;
}

__global__ __launch_bounds__(256)
void hist_kernel(const float* __restrict__ x, uint32_t* __restrict__ hist)
{
    const uint32_t p = blockIdx.x * 256u + threadIdx.x;
    atomicAdd(&hist[morton_key(x[p*3+0], x[p*3+1], x[p*3+2])], 1u);
}

__global__ __launch_bounds__(1024)
void scan_kernel(const uint32_t* __restrict__ hist, uint32_t* __restrict__ offs)
{
    __shared__ uint32_t part[1024];
    const uint32_t tid = threadIdx.x;
    uint32_t local[32];
    uint32_t sum = 0;
    #pragma unroll
    for (int i = 0; i < 32; ++i) { local[i] = hist[tid * 32u + i]; sum += local[i]; }
    part[tid] = sum;
    __syncthreads();
    for (uint32_t off = 1; off < 1024u; off <<= 1) {
        uint32_t v = (tid >= off) ? part[tid - off] : 0u;
        __syncthreads();
        part[tid] += v;
        __syncthreads();
    }
    uint32_t run = (tid ? part[tid - 1] : 0u);
    #pragma unroll
    for (int i = 0; i < 32; ++i) { offs[tid * 32u + i] = run; run += local[i]; }
}

__global__ __launch_bounds__(256)
void scatter_kernel(const float* __restrict__ x, uint32_t* __restrict__ offs,
                    float4* __restrict__ rec)
{
    const uint32_t p = blockIdx.x * 256u + threadIdx.x;
    const float x0 = x[p*3+0], x1 = x[p*3+1], x2 = x[p*3+2];
    const uint32_t pos = atomicAdd(&offs[morton_key(x0, x1, x2)], 1u);
    rec[pos] = make_float4(x0, x1, x2, __uint_as_float(p));
}

// ----------------------- dense-grid build (levels 0..4) --------------------
__global__ __launch_bounds__(256)
void build_grids(const float2* __restrict__ table, float2* __restrict__ gridbuf,
                 Params P)
{
    const uint32_t t = blockIdx.x * 256u + threadIdx.x;
    if (t >= P.vcum[NGRID]) return;
    uint32_t l = 0;
    #pragma unroll
    for (int i = 1; i < NGRID; ++i) if (t >= P.vcum[i]) l = i;
    const uint32_t v = t - P.vcum[l];
    const uint32_t d = P.gdim[l];
    const uint32_t vz = v / (d * d);
    const uint32_t r1 = v - vz * d * d;
    const uint32_t vy = r1 / d;
    const uint32_t vx = r1 - vy * d;
    const uint32_t h = ((vx ^ (vy * PR1) ^ (vz * PR2)) & TMASK) + (l << TBITS);
    gridbuf[P.goff[l] + v] = table[h];
}

// ------------------------- main gather (16 levels) -------------------------
__global__ __launch_bounds__(256)
void gather_sorted(const float4* __restrict__ rec,
                   const float2* __restrict__ table,
                   const float2* __restrict__ gridbuf,
                   __half2* __restrict__ stage,
                   Params P)
{
    const uint32_t l  = blockIdx.x / CHUNKS;     // level-phased for L2 residency
    const uint32_t sp = (blockIdx.x % CHUNKS) * 256u + threadIdx.x;
    const float4 r = rec[sp];
    float2 e;
    if (l < NGRID)
        e = eval_grid(r.x, r.y, r.z, P.s[l], gridbuf + P.goff[l], P.gdim[l]);
    else
        e = eval_hash(r.x, r.y, r.z, P.s[l], l, table);
    stage[l * NPTS + sp] = __floats2half2_rn(e.x, e.y);
}

// ---------------- transpose + un-permute (pure streaming) ------------------
__global__ __launch_bounds__(256)
void transpose_unperm(const float4* __restrict__ rec,
                      const __half2* __restrict__ stage,
                      float* __restrict__ out)
{
    const uint32_t sp = blockIdx.x * 256u + threadIdx.x;
    const uint32_t orig = __float_as_uint(rec[sp].w);
    float4 o[8];
    #pragma unroll
    for (int j = 0; j < 8; ++j) {
        const float2 a = __half22float2(stage[(uint32_t)(2*j)   * NPTS + sp]);
        const float2 b = __half22float2(stage[(uint32_t)(2*j+1) * NPTS + sp]);
        o[j] = make_float4(a.x, a.y, b.x, b.y);
    }
    float4* o4 = (float4*)(out + (size_t)orig * 32u);
    #pragma unroll
    for (int j = 0; j < 8; ++j) o4[j] = o[j];
}

// ------------------------------ fused fallback -----------------------------
__global__ __launch_bounds__(256)
void hashenc_fused(const float* __restrict__ x,
                   const float2* __restrict__ table,
                   float2* __restrict__ out,
                   Params P)
{
    const uint32_t tid = blockIdx.x * 256u + threadIdx.x;
    const uint32_t p = tid >> 4;
    const uint32_t l = tid & 15u;
    out[p * 16u + l] = eval_hash(x[p*3+0], x[p*3+1], x[p*3+2], P.s[l], l, table);
}

extern "C" void kernel_launch(void* const* d_in, const int* in_sizes, int n_in,
                              void* d_out, int out_size, void* d_ws, size_t ws_size,
                              hipStream_t stream) {
    const float*  x     = (const float*)d_in[0];
    const float2* table = (const float2*)d_in[1];

    // SCALINGS: replicate numpy float64 pipeline in identical op order.
    Params P;
    const double growth = exp((log(4096.0) - log(16.0)) / 15.0);
    for (int l = 0; l < NLVL; ++l)
        P.s[l] = (float)floor(16.0 * pow(growth, (double)l));

    uint32_t vtot = 0;
    for (int l = 0; l < NGRID; ++l) {
        const uint32_t d = (uint32_t)P.s[l] + 1u;   // vertices per axis
        P.gdim[l] = d;
        P.vcum[l] = vtot;
        P.goff[l] = vtot;
        vtot += d * d * d;
    }
    P.vcum[NGRID] = vtot;                            // ~533,601 vertices

    // ws layout: rec (16 MiB) | gridbuf (vtot*8B ~4.3 MiB, 256B-aligned) |
    //            stage fp16 (64 MiB)
    const size_t rec_bytes   = (size_t)NPTS * sizeof(float4);
    const size_t grid_bytes  = (((size_t)vtot * sizeof(float2)) + 255u) & ~(size_t)255u;
    const size_t stage_bytes = (size_t)NPTS * NLVL * sizeof(__half2);
    const size_t ws_needed   = rec_bytes + grid_bytes + stage_bytes;

    if (ws_size >= ws_needed) {
        float4*  rec     = (float4*)d_ws;
        float2*  gridbuf = (float2*)((char*)d_ws + rec_bytes);
        __half2* stage   = (__half2*)((char*)d_ws + rec_bytes + grid_bytes);
        uint32_t* hist = (uint32_t*)d_out;           // dead before out written
        uint32_t* offs = (uint32_t*)d_out + NBINS;

        dim3 b256(256u);
        hipLaunchKernelGGL(zero_hist_kernel, dim3(NBINS / 256u), b256, 0, stream, hist);
        hipLaunchKernelGGL(hist_kernel,      dim3(NPTS / 256u),  b256, 0, stream, x, hist);
        hipLaunchKernelGGL(scan_kernel,      dim3(1), dim3(1024u), 0, stream, hist, offs);
        hipLaunchKernelGGL(scatter_kernel,   dim3(NPTS / 256u),  b256, 0, stream, x, offs, rec);
        hipLaunchKernelGGL(build_grids,      dim3((vtot + 255u) / 256u), b256, 0, stream,
                           table, gridbuf, P);
        hipLaunchKernelGGL(gather_sorted,    dim3(NLVL * CHUNKS), b256, 0, stream,
                           rec, table, gridbuf, stage, P);
        hipLaunchKernelGGL(transpose_unperm, dim3(NPTS / 256u),  b256, 0, stream,
                           rec, stage, (float*)d_out);
    } else {
        float2* out = (float2*)d_out;
        hipLaunchKernelGGL(hashenc_fused, dim3(NPTS * NLVL / 256u), dim3(256u), 0, stream,
                           x, table, out, P);
    }
}

// Round 7
// 450.135 us; speedup vs baseline: 1.1695x; 1.0122x over previous
//
#include <hip/hip_runtime.h>
#include <hip/hip_fp16.h>
#include <math.h>

#define NPTS   (1u << 20)
#define NLVL   16
#define NGRID  5                 // levels 0..4 via dense vertex grids (4.3 MB)
#define NHASH  (NLVL - NGRID)    // 11 phased hash levels (5..15)
#define TBITS  19
#define TMASK  ((1u << TBITS) - 1u)
#define CHUNKS (NPTS / 256u)     // 4096 blocks per level
#define NBINS  32768             // 32^3 Morton buckets
#define PR1    2654435761u
#define PR2    805459861u

struct Params {
    float    s[NLVL];
    uint32_t gdim[NGRID];        // vertices per axis (s+1)
    uint32_t goff[NGRID];        // float2 offset of each grid in gridbuf
    uint32_t vcum[NGRID + 1];    // cumulative vertex counts
};

// ---------------------------------------------------------------------------
// Hash-path pair loader: fewest 64B-line touches (validated r3/r4 mechanism).
// ---------------------------------------------------------------------------
__device__ __forceinline__ void load_pair(const float2* __restrict__ t,
                                          uint32_t iF, uint32_t iC,
                                          float2& vF, float2& vC)
{
    const uint32_t d = iF ^ iC;
    if (d == 1u) {
        const float4 q = *(const float4*)(t + (iF & ~1u));
        if (iF & 1u) { vF = make_float2(q.z, q.w); vC = make_float2(q.x, q.y); }
        else         { vF = make_float2(q.x, q.y); vC = make_float2(q.z, q.w); }
    } else if (iC == iF + 1u || iF == iC + 1u) {
        const uint32_t lo = (iF < iC) ? iF : iC;
        const float4 q = *(const float4*)(t + lo);      // 8B-aligned dwordx4
        if (iF == lo) { vF = make_float2(q.x, q.y); vC = make_float2(q.z, q.w); }
        else          { vF = make_float2(q.z, q.w); vC = make_float2(q.x, q.y); }
    } else {
        vF = t[iF]; vC = t[iC];
    }
}

// Shared trilinear tail (bit-identical op order to the reference).
__device__ __forceinline__ float2 lerp8(float2 f0, float2 f1, float2 f2, float2 f3,
                                        float2 f4, float2 f5, float2 f6, float2 f7,
                                        float ox, float oy, float oz)
{
    const float omx = 1.0f - ox, omy = 1.0f - oy, omz = 1.0f - oz;
    const float a0 = f0.x * ox + f3.x * omx, b0 = f0.y * ox + f3.y * omx;
    const float a1 = f1.x * ox + f2.x * omx, b1 = f1.y * ox + f2.y * omx;
    const float a2 = f5.x * ox + f6.x * omx, b2 = f5.y * ox + f6.y * omx;
    const float a3 = f4.x * ox + f7.x * omx, b3 = f4.y * ox + f7.y * omx;
    const float c0 = a0 * oy + a1 * omy, d0 = b0 * oy + b1 * omy;
    const float c1 = a3 * oy + a2 * omy, d1 = b3 * oy + b2 * omy;
    return make_float2(c0 * oz + c1 * omz, d0 * oz + d1 * omz);
}

// Hash-table evaluation (levels >= NGRID).
__device__ __forceinline__ float2 eval_hash(float x0, float x1, float x2,
                                            float s, uint32_t l,
                                            const float2* __restrict__ table)
{
    const float sx = x0 * s, sy = x1 * s, sz = x2 * s;
    const float fxf = floorf(sx), fyf = floorf(sy), fzf = floorf(sz);
    const float cxf = ceilf(sx),  cyf = ceilf(sy),  czf = ceilf(sz);
    const float ox = sx - fxf, oy = sy - fyf, oz = sz - fzf;

    const uint32_t fx = (uint32_t)fxf, cx = (uint32_t)cxf;
    const uint32_t Yf = (uint32_t)fyf * PR1,  Yc = (uint32_t)cyf * PR1;
    const uint32_t Zf = (uint32_t)fzf * PR2,  Zc = (uint32_t)czf * PR2;
    const uint32_t base = l << TBITS;

    const uint32_t i0 = ((cx ^ Yc ^ Zc) & TMASK) + base;
    const uint32_t i1 = ((cx ^ Yf ^ Zc) & TMASK) + base;
    const uint32_t i2 = ((fx ^ Yf ^ Zc) & TMASK) + base;
    const uint32_t i3 = ((fx ^ Yc ^ Zc) & TMASK) + base;
    const uint32_t i4 = ((cx ^ Yc ^ Zf) & TMASK) + base;
    const uint32_t i5 = ((cx ^ Yf ^ Zf) & TMASK) + base;
    const uint32_t i6 = ((fx ^ Yf ^ Zf) & TMASK) + base;
    const uint32_t i7 = ((fx ^ Yc ^ Zf) & TMASK) + base;

    float2 f0, f1, f2, f3, f4, f5, f6, f7;
    load_pair(table, i3, i0, f3, f0);
    load_pair(table, i2, i1, f2, f1);
    load_pair(table, i7, i4, f7, f4);
    load_pair(table, i6, i5, f6, f5);
    return lerp8(f0, f1, f2, f3, f4, f5, f6, f7, ox, oy, oz);
}

// Dense-grid evaluation (levels < NGRID): grid[v] == table[hash(v)], corner
// values bit-identical; x-pairs contiguous -> one float4 per pair, always.
__device__ __forceinline__ float2 eval_grid(float x0, float x1, float x2,
                                            float s,
                                            const float2* __restrict__ g,
                                            uint32_t d)
{
    const float sx = x0 * s, sy = x1 * s, sz = x2 * s;
    const float fxf = floorf(sx), fyf = floorf(sy), fzf = floorf(sz);
    const float cxf = ceilf(sx),  cyf = ceilf(sy),  czf = ceilf(sz);
    const float ox = sx - fxf, oy = sy - fyf, oz = sz - fzf;

    const uint32_t fx = (uint32_t)fxf, fy = (uint32_t)fyf, fz = (uint32_t)fzf;
    const uint32_t cy = (uint32_t)cyf, cz = (uint32_t)czf;
    const bool xadj = ((uint32_t)cxf == fx + 1u);

    const uint32_t bA = (cz * d + cy) * d + fx;
    const uint32_t bB = (cz * d + fy) * d + fx;
    const uint32_t bC = (fz * d + cy) * d + fx;
    const uint32_t bD = (fz * d + fy) * d + fx;
    const float4 qA = *(const float4*)(g + bA);
    const float4 qB = *(const float4*)(g + bB);
    const float4 qC = *(const float4*)(g + bC);
    const float4 qD = *(const float4*)(g + bD);

    const float2 f3 = make_float2(qA.x, qA.y);
    const float2 f0 = xadj ? make_float2(qA.z, qA.w) : f3;
    const float2 f2 = make_float2(qB.x, qB.y);
    const float2 f1 = xadj ? make_float2(qB.z, qB.w) : f2;
    const float2 f7 = make_float2(qC.x, qC.y);
    const float2 f4 = xadj ? make_float2(qC.z, qC.w) : f7;
    const float2 f6 = make_float2(qD.x, qD.y);
    const float2 f5 = xadj ? make_float2(qD.z, qD.w) : f6;
    return lerp8(f0, f1, f2, f3, f4, f5, f6, f7, ox, oy, oz);
}

// --------------------------- Morton key (32^3) -----------------------------
__device__ __forceinline__ uint32_t part1by2(uint32_t v)
{
    v &= 0x3FFu;
    v = (v | (v << 16)) & 0x030000FFu;
    v = (v | (v << 8))  & 0x0300F00Fu;
    v = (v | (v << 4))  & 0x030C30C3u;
    v = (v | (v << 2))  & 0x09249249u;
    return v;
}
__device__ __forceinline__ uint32_t morton_key(float x0, float x1, float x2)
{
    uint32_t kx = (uint32_t)(x0 * 32.0f); kx = kx > 31u ? 31u : kx;
    uint32_t ky = (uint32_t)(x1 * 32.0f); ky = ky > 31u ? 31u : ky;
    uint32_t kz = (uint32_t)(x2 * 32.0f); kz = kz > 31u ? 31u : kz;
    return part1by2(kx) | (part1by2(ky) << 1) | (part1by2(kz) << 2);
}

// ------------------------------ sort kernels -------------------------------
__global__ __launch_bounds__(256)
void zero_hist_kernel(uint32_t* __restrict__ hist)
{
    hist[blockIdx.x * 256u + threadIdx.x] = 0u;
}

__global__ __launch_bounds__(256)
void hist_kernel(const float* __restrict__ x, uint32_t* __restrict__ hist)
{
    const uint32_t p = blockIdx.x * 256u + threadIdx.x;
    atomicAdd(&hist[morton_key(x[p*3+0], x[p*3+1], x[p*3+2])], 1u);
}

__global__ __launch_bounds__(1024)
void scan_kernel(const uint32_t* __restrict__ hist, uint32_t* __restrict__ offs)
{
    __shared__ uint32_t part[1024];
    const uint32_t tid = threadIdx.x;
    uint32_t local[32];
    uint32_t sum = 0;
    #pragma unroll
    for (int i = 0; i < 32; ++i) { local[i] = hist[tid * 32u + i]; sum += local[i]; }
    part[tid] = sum;
    __syncthreads();
    for (uint32_t off = 1; off < 1024u; off <<= 1) {
        uint32_t v = (tid >= off) ? part[tid - off] : 0u;
        __syncthreads();
        part[tid] += v;
        __syncthreads();
    }
    uint32_t run = (tid ? part[tid - 1] : 0u);
    #pragma unroll
    for (int i = 0; i < 32; ++i) { offs[tid * 32u + i] = run; run += local[i]; }
}

__global__ __launch_bounds__(256)
void scatter_kernel(const float* __restrict__ x, uint32_t* __restrict__ offs,
                    float4* __restrict__ rec)
{
    const uint32_t p = blockIdx.x * 256u + threadIdx.x;
    const float x0 = x[p*3+0], x1 = x[p*3+1], x2 = x[p*3+2];
    const uint32_t pos = atomicAdd(&offs[morton_key(x0, x1, x2)], 1u);
    rec[pos] = make_float4(x0, x1, x2, __uint_as_float(p));
}

// ----------------------- dense-grid build (levels 0..4) --------------------
__global__ __launch_bounds__(256)
void build_grids(const float2* __restrict__ table, float2* __restrict__ gridbuf,
                 Params P)
{
    const uint32_t t = blockIdx.x * 256u + threadIdx.x;
    if (t >= P.vcum[NGRID]) return;
    uint32_t l = 0;
    #pragma unroll
    for (int i = 1; i < NGRID; ++i) if (t >= P.vcum[i]) l = i;
    const uint32_t v = t - P.vcum[l];
    const uint32_t d = P.gdim[l];
    const uint32_t vz = v / (d * d);
    const uint32_t r1 = v - vz * d * d;
    const uint32_t vy = r1 / d;
    const uint32_t vx = r1 - vy * d;
    const uint32_t h = ((vx ^ (vy * PR1) ^ (vz * PR2)) & TMASK) + (l << TBITS);
    gridbuf[P.goff[l] + v] = table[h];
}

// ------------------- phased gather: hash levels 5..15 only -----------------
__global__ __launch_bounds__(256)
void gather_hash(const float4* __restrict__ rec,
                 const float2* __restrict__ table,
                 __half2* __restrict__ stage,
                 Params P)
{
    const uint32_t j  = blockIdx.x / CHUNKS;     // 0..10 -> level 5+j
    const uint32_t l  = NGRID + j;
    const uint32_t sp = (blockIdx.x % CHUNKS) * 256u + threadIdx.x;
    const float4 r = rec[sp];
    const float2 e = eval_hash(r.x, r.y, r.z, P.s[l], l, table);
    stage[j * NPTS + sp] = __floats2half2_rn(e.x, e.y);
}

// ------ finish: inline grid levels 0..4 + stage readback + unperm write ----
__global__ __launch_bounds__(256)
void finish_kernel(const float4* __restrict__ rec,
                   const __half2* __restrict__ stage,
                   const float2* __restrict__ gridbuf,
                   float* __restrict__ out,
                   Params P)
{
    const uint32_t sp = blockIdx.x * 256u + threadIdx.x;
    const float4 r = rec[sp];
    const uint32_t orig = __float_as_uint(r.w);

    float2 v[NLVL];
    #pragma unroll
    for (int l = 0; l < NGRID; ++l)
        v[l] = eval_grid(r.x, r.y, r.z, P.s[l], gridbuf + P.goff[l], P.gdim[l]);
    #pragma unroll
    for (int j = 0; j < NHASH; ++j)
        v[NGRID + j] = __half22float2(stage[(uint32_t)j * NPTS + sp]);

    float4* o4 = (float4*)(out + (size_t)orig * 32u);
    #pragma unroll
    for (int j = 0; j < 8; ++j)
        o4[j] = make_float4(v[2*j].x, v[2*j].y, v[2*j+1].x, v[2*j+1].y);
}

// ------------------------------ fused fallback -----------------------------
__global__ __launch_bounds__(256)
void hashenc_fused(const float* __restrict__ x,
                   const float2* __restrict__ table,
                   float2* __restrict__ out,
                   Params P)
{
    const uint32_t tid = blockIdx.x * 256u + threadIdx.x;
    const uint32_t p = tid >> 4;
    const uint32_t l = tid & 15u;
    out[p * 16u + l] = eval_hash(x[p*3+0], x[p*3+1], x[p*3+2], P.s[l], l, table);
}

extern "C" void kernel_launch(void* const* d_in, const int* in_sizes, int n_in,
                              void* d_out, int out_size, void* d_ws, size_t ws_size,
                              hipStream_t stream) {
    const float*  x     = (const float*)d_in[0];
    const float2* table = (const float2*)d_in[1];

    // SCALINGS: replicate numpy float64 pipeline in identical op order.
    Params P;
    const double growth = exp((log(4096.0) - log(16.0)) / 15.0);
    for (int l = 0; l < NLVL; ++l)
        P.s[l] = (float)floor(16.0 * pow(growth, (double)l));

    uint32_t vtot = 0;
    for (int l = 0; l < NGRID; ++l) {
        const uint32_t d = (uint32_t)P.s[l] + 1u;
        P.gdim[l] = d;
        P.vcum[l] = vtot;
        P.goff[l] = vtot;
        vtot += d * d * d;
    }
    P.vcum[NGRID] = vtot;                            // 533,601 vertices

    // ws: rec (16 MiB) | gridbuf (~4.3 MiB) | stage fp16 11 levels (44 MiB)
    const size_t rec_bytes   = (size_t)NPTS * sizeof(float4);
    const size_t grid_bytes  = (((size_t)vtot * sizeof(float2)) + 255u) & ~(size_t)255u;
    const size_t stage_bytes = (size_t)NPTS * NHASH * sizeof(__half2);
    const size_t ws_needed   = rec_bytes + grid_bytes + stage_bytes;

    if (ws_size >= ws_needed) {
        float4*  rec     = (float4*)d_ws;
        float2*  gridbuf = (float2*)((char*)d_ws + rec_bytes);
        __half2* stage   = (__half2*)((char*)d_ws + rec_bytes + grid_bytes);
        uint32_t* hist = (uint32_t*)d_out;           // dead before out written
        uint32_t* offs = (uint32_t*)d_out + NBINS;

        dim3 b256(256u);
        hipLaunchKernelGGL(zero_hist_kernel, dim3(NBINS / 256u), b256, 0, stream, hist);
        hipLaunchKernelGGL(hist_kernel,      dim3(NPTS / 256u),  b256, 0, stream, x, hist);
        hipLaunchKernelGGL(scan_kernel,      dim3(1), dim3(1024u), 0, stream, hist, offs);
        hipLaunchKernelGGL(scatter_kernel,   dim3(NPTS / 256u),  b256, 0, stream, x, offs, rec);
        hipLaunchKernelGGL(build_grids,      dim3((vtot + 255u) / 256u), b256, 0, stream,
                           table, gridbuf, P);
        hipLaunchKernelGGL(gather_hash,      dim3(NHASH * CHUNKS), b256, 0, stream,
                           rec, table, stage, P);
        hipLaunchKernelGGL(finish_kernel,    dim3(NPTS / 256u),  b256, 0, stream,
                           rec, stage, gridbuf, (float*)d_out, P);
    } else {
        float2* out = (float2*)d_out;
        hipLaunchKernelGGL(hashenc_fused, dim3(NPTS * NLVL / 256u), dim3(256u), 0, stream,
                           x, table, out, P);
    }
}

// Round 8
// 378.696 us; speedup vs baseline: 1.3901x; 1.1886x over previous
//
#include <hip/hip_runtime.h>
#include <hip/hip_fp16.h>
#include <math.h>

#define NPTS   (1u << 20)
#define NLVL   16
#define NGRID  5                 // levels 0..4 via dense vertex grids (4.3 MB)
#define TBITS  19
#define TMASK  ((1u << TBITS) - 1u)
#define CHUNKS (NPTS / 256u)     // 4096 blocks per level-phase
#define PR1    2654435761u
#define PR2    805459861u

struct Params {
    float    s[NLVL];
    uint32_t gdim[NGRID];        // vertices per axis (s+1)
    uint32_t goff[NGRID];        // float2 offset of each grid in gridbuf
    uint32_t vcum[NGRID + 1];    // cumulative vertex counts
};

// ---------------------------------------------------------------------------
// Hash-path pair loader: fewest 64B-line requests (validated r3/r4 mechanism).
// ---------------------------------------------------------------------------
__device__ __forceinline__ void load_pair(const float2* __restrict__ t,
                                          uint32_t iF, uint32_t iC,
                                          float2& vF, float2& vC)
{
    const uint32_t d = iF ^ iC;
    if (d == 1u) {
        const float4 q = *(const float4*)(t + (iF & ~1u));
        if (iF & 1u) { vF = make_float2(q.z, q.w); vC = make_float2(q.x, q.y); }
        else         { vF = make_float2(q.x, q.y); vC = make_float2(q.z, q.w); }
    } else if (iC == iF + 1u || iF == iC + 1u) {
        const uint32_t lo = (iF < iC) ? iF : iC;
        const float4 q = *(const float4*)(t + lo);      // 8B-aligned dwordx4
        if (iF == lo) { vF = make_float2(q.x, q.y); vC = make_float2(q.z, q.w); }
        else          { vF = make_float2(q.z, q.w); vC = make_float2(q.x, q.y); }
    } else {
        vF = t[iF]; vC = t[iC];
    }
}

// Shared trilinear tail (bit-identical op order to the reference).
__device__ __forceinline__ float2 lerp8(float2 f0, float2 f1, float2 f2, float2 f3,
                                        float2 f4, float2 f5, float2 f6, float2 f7,
                                        float ox, float oy, float oz)
{
    const float omx = 1.0f - ox, omy = 1.0f - oy, omz = 1.0f - oz;
    const float a0 = f0.x * ox + f3.x * omx, b0 = f0.y * ox + f3.y * omx;
    const float a1 = f1.x * ox + f2.x * omx, b1 = f1.y * ox + f2.y * omx;
    const float a2 = f5.x * ox + f6.x * omx, b2 = f5.y * ox + f6.y * omx;
    const float a3 = f4.x * ox + f7.x * omx, b3 = f4.y * ox + f7.y * omx;
    const float c0 = a0 * oy + a1 * omy, d0 = b0 * oy + b1 * omy;
    const float c1 = a3 * oy + a2 * omy, d1 = b3 * oy + b2 * omy;
    return make_float2(c0 * oz + c1 * omz, d0 * oz + d1 * omz);
}

// Hash-table evaluation (levels >= NGRID).
__device__ __forceinline__ float2 eval_hash(float x0, float x1, float x2,
                                            float s, uint32_t l,
                                            const float2* __restrict__ table)
{
    const float sx = x0 * s, sy = x1 * s, sz = x2 * s;
    const float fxf = floorf(sx), fyf = floorf(sy), fzf = floorf(sz);
    const float cxf = ceilf(sx),  cyf = ceilf(sy),  czf = ceilf(sz);
    const float ox = sx - fxf, oy = sy - fyf, oz = sz - fzf;

    const uint32_t fx = (uint32_t)fxf, cx = (uint32_t)cxf;
    const uint32_t Yf = (uint32_t)fyf * PR1,  Yc = (uint32_t)cyf * PR1;
    const uint32_t Zf = (uint32_t)fzf * PR2,  Zc = (uint32_t)czf * PR2;
    const uint32_t base = l << TBITS;

    const uint32_t i0 = ((cx ^ Yc ^ Zc) & TMASK) + base;
    const uint32_t i1 = ((cx ^ Yf ^ Zc) & TMASK) + base;
    const uint32_t i2 = ((fx ^ Yf ^ Zc) & TMASK) + base;
    const uint32_t i3 = ((fx ^ Yc ^ Zc) & TMASK) + base;
    const uint32_t i4 = ((cx ^ Yc ^ Zf) & TMASK) + base;
    const uint32_t i5 = ((cx ^ Yf ^ Zf) & TMASK) + base;
    const uint32_t i6 = ((fx ^ Yf ^ Zf) & TMASK) + base;
    const uint32_t i7 = ((fx ^ Yc ^ Zf) & TMASK) + base;

    float2 f0, f1, f2, f3, f4, f5, f6, f7;
    load_pair(table, i3, i0, f3, f0);
    load_pair(table, i2, i1, f2, f1);
    load_pair(table, i7, i4, f7, f4);
    load_pair(table, i6, i5, f6, f5);
    return lerp8(f0, f1, f2, f3, f4, f5, f6, f7, ox, oy, oz);
}

// Dense-grid evaluation (levels < NGRID): grid[v] == table[hash(v)], corner
// values bit-identical; x-pairs contiguous -> one float4 per pair, always.
__device__ __forceinline__ float2 eval_grid(float x0, float x1, float x2,
                                            float s,
                                            const float2* __restrict__ g,
                                            uint32_t d)
{
    const float sx = x0 * s, sy = x1 * s, sz = x2 * s;
    const float fxf = floorf(sx), fyf = floorf(sy), fzf = floorf(sz);
    const float cxf = ceilf(sx),  cyf = ceilf(sy),  czf = ceilf(sz);
    const float ox = sx - fxf, oy = sy - fyf, oz = sz - fzf;

    const uint32_t fx = (uint32_t)fxf, fy = (uint32_t)fyf, fz = (uint32_t)fzf;
    const uint32_t cy = (uint32_t)cyf, cz = (uint32_t)czf;
    const bool xadj = ((uint32_t)cxf == fx + 1u);

    const uint32_t bA = (cz * d + cy) * d + fx;
    const uint32_t bB = (cz * d + fy) * d + fx;
    const uint32_t bC = (fz * d + cy) * d + fx;
    const uint32_t bD = (fz * d + fy) * d + fx;
    const float4 qA = *(const float4*)(g + bA);
    const float4 qB = *(const float4*)(g + bB);
    const float4 qC = *(const float4*)(g + bC);
    const float4 qD = *(const float4*)(g + bD);

    const float2 f3 = make_float2(qA.x, qA.y);
    const float2 f0 = xadj ? make_float2(qA.z, qA.w) : f3;
    const float2 f2 = make_float2(qB.x, qB.y);
    const float2 f1 = xadj ? make_float2(qB.z, qB.w) : f2;
    const float2 f7 = make_float2(qC.x, qC.y);
    const float2 f4 = xadj ? make_float2(qC.z, qC.w) : f7;
    const float2 f6 = make_float2(qD.x, qD.y);
    const float2 f5 = xadj ? make_float2(qD.z, qD.w) : f6;
    return lerp8(f0, f1, f2, f3, f4, f5, f6, f7, ox, oy, oz);
}

// ----------------------- dense-grid build (levels 0..4) --------------------
__global__ __launch_bounds__(256)
void build_grids(const float2* __restrict__ table, float2* __restrict__ gridbuf,
                 Params P)
{
    const uint32_t t = blockIdx.x * 256u + threadIdx.x;
    if (t >= P.vcum[NGRID]) return;
    uint32_t l = 0;
    #pragma unroll
    for (int i = 1; i < NGRID; ++i) if (t >= P.vcum[i]) l = i;
    const uint32_t v = t - P.vcum[l];
    const uint32_t d = P.gdim[l];
    const uint32_t vz = v / (d * d);
    const uint32_t r1 = v - vz * d * d;
    const uint32_t vy = r1 / d;
    const uint32_t vx = r1 - vy * d;
    const uint32_t h = ((vx ^ (vy * PR1) ^ (vz * PR2)) & TMASK) + (l << TBITS);
    gridbuf[P.goff[l] + v] = table[h];
}

// -------------- phased gather, ORIGINAL point order, all 16 levels ---------
__global__ __launch_bounds__(256)
void gather16(const float* __restrict__ x,
              const float2* __restrict__ table,
              const float2* __restrict__ gridbuf,
              __half2* __restrict__ stage,
              Params P)
{
    const uint32_t l = blockIdx.x / CHUNKS;     // level-phased for L2 residency
    const uint32_t p = (blockIdx.x % CHUNKS) * 256u + threadIdx.x;

    const float x0 = x[p * 3 + 0];
    const float x1 = x[p * 3 + 1];
    const float x2 = x[p * 3 + 2];

    float2 e;
    if (l < NGRID)
        e = eval_grid(x0, x1, x2, P.s[l], gridbuf + P.goff[l], P.gdim[l]);
    else
        e = eval_hash(x0, x1, x2, P.s[l], l, table);
    stage[l * NPTS + p] = __floats2half2_rn(e.x, e.y);
}

// ------------- transpose [l][p] -> [p][l], identity order, coalesced -------
__global__ __launch_bounds__(256)
void transpose_kernel(const __half2* __restrict__ stage, float4* __restrict__ out4)
{
    const uint32_t e = blockIdx.x * 256u + threadIdx.x;  // = p*8 + j
    const uint32_t p = e >> 3;
    const uint32_t j = e & 7u;
    const float2 a = __half22float2(stage[(2u*j)     * NPTS + p]);
    const float2 b = __half22float2(stage[(2u*j + 1) * NPTS + p]);
    out4[e] = make_float4(a.x, a.y, b.x, b.y);
}

// ------------------------------ fused fallback -----------------------------
__global__ __launch_bounds__(256)
void hashenc_fused(const float* __restrict__ x,
                   const float2* __restrict__ table,
                   float2* __restrict__ out,
                   Params P)
{
    const uint32_t tid = blockIdx.x * 256u + threadIdx.x;
    const uint32_t p = tid >> 4;
    const uint32_t l = tid & 15u;
    out[p * 16u + l] = eval_hash(x[p*3+0], x[p*3+1], x[p*3+2], P.s[l], l, table);
}

extern "C" void kernel_launch(void* const* d_in, const int* in_sizes, int n_in,
                              void* d_out, int out_size, void* d_ws, size_t ws_size,
                              hipStream_t stream) {
    const float*  x     = (const float*)d_in[0];
    const float2* table = (const float2*)d_in[1];

    // SCALINGS: replicate numpy float64 pipeline in identical op order.
    Params P;
    const double growth = exp((log(4096.0) - log(16.0)) / 15.0);
    for (int l = 0; l < NLVL; ++l)
        P.s[l] = (float)floor(16.0 * pow(growth, (double)l));

    uint32_t vtot = 0;
    for (int l = 0; l < NGRID; ++l) {
        const uint32_t d = (uint32_t)P.s[l] + 1u;
        P.gdim[l] = d;
        P.vcum[l] = vtot;
        P.goff[l] = vtot;
        vtot += d * d * d;
    }
    P.vcum[NGRID] = vtot;                            // 533,601 vertices

    // ws: gridbuf (~4.3 MiB, 256B-aligned) | stage fp16 16 levels (64 MiB)
    const size_t grid_bytes  = (((size_t)vtot * sizeof(float2)) + 255u) & ~(size_t)255u;
    const size_t stage_bytes = (size_t)NPTS * NLVL * sizeof(__half2);
    const size_t ws_needed   = grid_bytes + stage_bytes;

    if (ws_size >= ws_needed) {
        float2*  gridbuf = (float2*)d_ws;
        __half2* stage   = (__half2*)((char*)d_ws + grid_bytes);
        float4*  out4    = (float4*)d_out;

        dim3 b256(256u);
        hipLaunchKernelGGL(build_grids, dim3((vtot + 255u) / 256u), b256, 0, stream,
                           table, gridbuf, P);
        hipLaunchKernelGGL(gather16, dim3(NLVL * CHUNKS), b256, 0, stream,
                           x, table, gridbuf, stage, P);
        hipLaunchKernelGGL(transpose_kernel, dim3(NPTS * 8u / 256u), b256, 0, stream,
                           stage, out4);
    } else {
        float2* out = (float2*)d_out;
        hipLaunchKernelGGL(hashenc_fused, dim3(NPTS * NLVL / 256u), dim3(256u), 0, stream,
                           x, table, out, P);
    }
}